// Round 5
// baseline (149.610 us; speedup 1.0000x reference)
//
#include <hip/hip_runtime.h>
#include <hip/hip_bf16.h>
#include <math.h>

#define B_TOT 8192
#define OBS   4096
#define NG    4
#define GSZ   1024
#define LATD  64
#define HDIM  128

typedef __attribute__((ext_vector_type(8))) short   short8_t;
typedef __attribute__((ext_vector_type(8))) unsigned short ushort8_t;
typedef __attribute__((ext_vector_type(4))) float   float4_t;

__constant__ int kMask[15] = {1,2,4,8, 3,5,9,6,10,12, 7,11,13,14, 15};

static __device__ __forceinline__ unsigned short f2b(float x) {
  __hip_bfloat16 b = __float2bfloat16(x);
  return *reinterpret_cast<unsigned short*>(&b);
}
static __device__ __forceinline__ unsigned int pack2(float lo, float hi) {
  return (unsigned int)f2b(lo) | ((unsigned int)f2b(hi) << 16);
}

// ---------------- weight prep: transpose + bf16 ----------------------------
// W1t[(g*128+h)*1024+k]=enc_w1[g][k][h]   N1=524288
// W2t[(g*128+o)*128+k]=enc_w2[g][k][o]    N2=65536
// W3t[(g*64+m)*64+k]  =dec_w1[g][k][m]    N3=16384
// W4t[(g*1024+o)*64+k]=dec_w2[g][k][o]    N4=262144
#define N1 524288
#define N2 65536
#define N3 16384
#define N4 262144
__global__ __launch_bounds__(256) void k_prep(const float* __restrict__ w1,
                                              const float* __restrict__ w2,
                                              const float* __restrict__ w3,
                                              const float* __restrict__ w4,
                                              unsigned short* __restrict__ W1t,
                                              unsigned short* __restrict__ W2t,
                                              unsigned short* __restrict__ W3t,
                                              unsigned short* __restrict__ W4t) {
  const int i = blockIdx.x * 256 + threadIdx.x;
  if (i < N1) {
    const int g = i >> 17, rem = i & 131071;
    const int h = rem >> 10, k = rem & 1023;
    W1t[i] = f2b(w1[g * 131072 + k * 128 + h]);
  } else if (i < N1 + N2) {
    const int idx = i - N1;
    const int g = idx >> 14, rem = idx & 16383;
    const int o = rem >> 7, k = rem & 127;
    W2t[idx] = f2b(w2[g * 16384 + k * 128 + o]);
  } else if (i < N1 + N2 + N3) {
    const int idx = i - N1 - N2;
    const int g = idx >> 12, rem = idx & 4095;
    const int m = rem >> 6, k = rem & 63;
    W3t[idx] = f2b(w3[g * 4096 + k * 64 + m]);
  } else if (i < N1 + N2 + N3 + N4) {
    const int idx = i - N1 - N2 - N3;
    const int g = idx >> 16, rem = idx & 65535;
    const int o = rem >> 6, k = rem & 63;
    W4t[idx] = f2b(w4[g * 65536 + k * 1024 + o]);
  }
}

// ---------------- X transpose: Xt[b][g][k] = bf16(X[b][4k+g]) --------------
// 8192 blocks x 512 thr; thread t: 8 consecutive floats -> 1 u32 per g-plane.
__global__ __launch_bounds__(512) void k_prepx(const float* __restrict__ X,
                                               unsigned short* __restrict__ Xt) {
  const int b = blockIdx.x;
  const int t = threadIdx.x;
  const float* p = X + (size_t)b * OBS + t * 8;
  const float4 f0 = *(const float4*)(p);
  const float4 f1 = *(const float4*)(p + 4);
  const float a0[4] = {f0.x, f0.y, f0.z, f0.w};
  const float a1[4] = {f1.x, f1.y, f1.z, f1.w};
  unsigned int* q = (unsigned int*)(Xt + (size_t)b * OBS);
#pragma unroll
  for (int g = 0; g < 4; ++g)
    q[g * 512 + t] = pack2(a0[g], a1[g]);
}

// ---------------- fused encoder: enc1 -> enc2 -> PoE/sample -> dec1 --------
// 256 blocks x 512 thr. Block = 32 batch rows. Wave w: g=w>>1, hh=(w&1)*64.
// Phase1 (enc1): barrier-free K=1024 loop, A from Xt global, B from W1t (L2).
// Phase2 (enc2): A from LDS h-planes, B from W2t (L2), 4 ksteps, no barriers.
// Phase3: PoE+sample in LDS. Phase4 (dec1): A=z from LDS, B from W3t -> Hd.
struct EncLds {
  union {
    unsigned short hp[16][32][40];   // [plane=ks*4+g][row][off 0..31 +8pad]
    float mls[32][516];
  } u;
  unsigned short zb[32][72];         // z bf16, row stride 144B
};
__global__ __launch_bounds__(512, 2) void k_enc(const unsigned short* __restrict__ Xt,
                                                const unsigned short* __restrict__ W1t,
                                                const unsigned short* __restrict__ W2t,
                                                const unsigned short* __restrict__ W3t,
                                                const float* __restrict__ B1,
                                                const float* __restrict__ B2,
                                                const float* __restrict__ DB1,
                                                const float* __restrict__ eps,
                                                const int*   __restrict__ subset_idx,
                                                unsigned short* __restrict__ Hd) {
  __shared__ EncLds s;
  const int tid = threadIdx.x;
  const int w   = tid >> 6;
  const int l   = tid & 63;
  const int g   = w >> 1;
  const int hh  = (w & 1) * 64;
  const int rb  = blockIdx.x * 32;
  const int l15 = l & 15;
  const int oct = l >> 4;

  float4_t acc[2][4];
#pragma unroll
  for (int i = 0; i < 2; ++i)
#pragma unroll
    for (int j = 0; j < 4; ++j) acc[i][j] = (float4_t){0.f, 0.f, 0.f, 0.f};

  // ---- phase 1: enc1, K=1024, 32 ksteps, NO barriers ----
  {
    const unsigned short* abase = Xt + (size_t)(rb + l15) * OBS + g * GSZ + oct * 8;
    const unsigned short* bbase = W1t + (size_t)(g * 128 + hh + l15) * GSZ + oct * 8;
#pragma unroll 4
    for (int ks = 0; ks < 32; ++ks) {
      short8_t af[2], bf[4];
#pragma unroll
      for (int mi = 0; mi < 2; ++mi)
        af[mi] = *(const short8_t*)(abase + (size_t)mi * 16 * OBS + ks * 32);
#pragma unroll
      for (int ni = 0; ni < 4; ++ni)
        bf[ni] = *(const short8_t*)(bbase + (size_t)ni * 16 * GSZ + ks * 32);
#pragma unroll
      for (int mi = 0; mi < 2; ++mi)
#pragma unroll
        for (int ni = 0; ni < 4; ++ni)
          acc[mi][ni] = __builtin_amdgcn_mfma_f32_16x16x32_bf16(af[mi], bf[ni], acc[mi][ni], 0, 0, 0);
    }
  }

  // h = relu(acc + b1) -> LDS planes
#pragma unroll
  for (int ni = 0; ni < 4; ++ni) {
    const int cg    = hh + ni * 16 + l15;     // col within group, 0..127
    const int plane = (cg >> 5) * 4 + g;
    const int off   = cg & 31;
    const float b   = B1[g * 128 + cg];
#pragma unroll
    for (int mi = 0; mi < 2; ++mi) {
      const int row = mi * 16 + oct * 4;
#pragma unroll
      for (int j = 0; j < 4; ++j)
        s.u.hp[plane][row + j][off] = f2b(fmaxf(acc[mi][ni][j] + b, 0.0f));
    }
  }
  __syncthreads();

  // ---- phase 2: enc2, K=128 (own group), 4 ksteps, no barriers ----
#pragma unroll
  for (int i = 0; i < 2; ++i)
#pragma unroll
    for (int j = 0; j < 4; ++j) acc[i][j] = (float4_t){0.f, 0.f, 0.f, 0.f};
  {
    const unsigned short* bbase = W2t + (size_t)(g * 128 + hh + l15) * HDIM + oct * 8;
#pragma unroll
    for (int ks = 0; ks < 4; ++ks) {
      short8_t af[2], bf[4];
#pragma unroll
      for (int mi = 0; mi < 2; ++mi)
        af[mi] = *(const short8_t*)(&s.u.hp[ks * 4 + g][mi * 16 + l15][oct * 8]);
#pragma unroll
      for (int ni = 0; ni < 4; ++ni)
        bf[ni] = *(const short8_t*)(bbase + (size_t)ni * 16 * HDIM + ks * 32);
#pragma unroll
      for (int mi = 0; mi < 2; ++mi)
#pragma unroll
        for (int ni = 0; ni < 4; ++ni)
          acc[mi][ni] = __builtin_amdgcn_mfma_f32_16x16x32_bf16(af[mi], bf[ni], acc[mi][ni], 0, 0, 0);
    }
  }
  __syncthreads();   // done reading hp; mls overlays it

#pragma unroll
  for (int ni = 0; ni < 4; ++ni) {
    const int col = g * 128 + hh + ni * 16 + l15;
    const float b = B2[col];
#pragma unroll
    for (int mi = 0; mi < 2; ++mi)
#pragma unroll
      for (int j = 0; j < 4; ++j)
        s.u.mls[mi * 16 + oct * 4 + j][col] = acc[mi][ni][j] + b;
  }
  __syncthreads();

  // ---- phase 3: PoE + reparameterize -> zb (bf16) ----
#pragma unroll
  for (int q = 0; q < 4; ++q) {
    const int idx = q * 512 + tid;
    const int r   = idx >> 6;
    const int ll  = idx & 63;
    const int m   = kMask[subset_idx[rb + r]];
    float tau = 1.0f, num = 0.0f;
#pragma unroll
    for (int gg = 0; gg < 4; ++gg) {
      if (m & (1 << gg)) {
        const float lv = s.u.mls[r][gg * 128 + 64 + ll];
        const float mu = s.u.mls[r][gg * 128 + ll];
        const float t  = expf(-lv);
        tau += t;
        num = fmaf(t, mu, num);
      }
    }
    const float zv = num / tau + eps[(size_t)(rb + r) * LATD + ll] * rsqrtf(tau);
    s.zb[r][ll] = f2b(zv);
  }
  __syncthreads();

  // ---- phase 4: dec1, K=64, 2 ksteps -> Hd bf16 ----
  const int mh = (w & 1) * 32;
  float4_t a3[2][2];
#pragma unroll
  for (int i = 0; i < 2; ++i)
#pragma unroll
    for (int j = 0; j < 2; ++j) a3[i][j] = (float4_t){0.f, 0.f, 0.f, 0.f};
  {
    const unsigned short* bbase = W3t + (size_t)(g * 64 + mh + l15) * LATD + oct * 8;
#pragma unroll
    for (int ks = 0; ks < 2; ++ks) {
      short8_t af[2], bf[2];
#pragma unroll
      for (int mi = 0; mi < 2; ++mi)
        af[mi] = *(const short8_t*)(&s.zb[mi * 16 + l15][ks * 32 + oct * 8]);
#pragma unroll
      for (int ni = 0; ni < 2; ++ni)
        bf[ni] = *(const short8_t*)(bbase + (size_t)ni * 16 * LATD + ks * 32);
#pragma unroll
      for (int mi = 0; mi < 2; ++mi)
#pragma unroll
        for (int ni = 0; ni < 2; ++ni)
          a3[mi][ni] = __builtin_amdgcn_mfma_f32_16x16x32_bf16(af[mi], bf[ni], a3[mi][ni], 0, 0, 0);
    }
  }
#pragma unroll
  for (int ni = 0; ni < 2; ++ni) {
    const int col = g * 64 + mh + ni * 16 + l15;   // 0..255
    const float b = DB1[col];
#pragma unroll
    for (int mi = 0; mi < 2; ++mi) {
      const int row = mi * 16 + oct * 4;
#pragma unroll
      for (int j = 0; j < 4; ++j)
        Hd[(size_t)(rb + row + j) * 256 + col] = f2b(fmaxf(a3[mi][ni][j] + b, 0.0f));
    }
  }
}

// ---------------- dec2: direct-global MFMA + coalesced epilogue ------------
__global__ __launch_bounds__(512) void k_dec2(const unsigned short* __restrict__ Hd,
                                              const unsigned short* __restrict__ W4t,
                                              const float* __restrict__ Bb,
                                              float* __restrict__ Out) {
  __shared__ float obuf[32][264];

  const int tid = threadIdx.x;
  const int w   = tid >> 6;
  const int l   = tid & 63;
  const int g   = w >> 1;
  const int ohh = (w & 1) * 32;
  const int r0  = blockIdx.x * 32;
  const int ob  = blockIdx.y * 64;
  const int l15 = l & 15;
  const int oct = l >> 4;

  float4_t acc[2][2];
#pragma unroll
  for (int i = 0; i < 2; ++i)
#pragma unroll
    for (int j = 0; j < 2; ++j) acc[i][j] = (float4_t){0.f, 0.f, 0.f, 0.f};

#pragma unroll
  for (int ks = 0; ks < 2; ++ks) {
    short8_t af[2], bf[2];
#pragma unroll
    for (int mi = 0; mi < 2; ++mi)
      af[mi] = *(const short8_t*)(Hd + (size_t)(r0 + mi * 16 + l15) * 256 +
                                  g * 64 + ks * 32 + oct * 8);
#pragma unroll
    for (int ni = 0; ni < 2; ++ni)
      bf[ni] = *(const short8_t*)(W4t + (size_t)(g * 1024 + ob + ohh + ni * 16 + l15) * 64 +
                                  ks * 32 + oct * 8);
#pragma unroll
    for (int mi = 0; mi < 2; ++mi)
#pragma unroll
      for (int ni = 0; ni < 2; ++ni)
        acc[mi][ni] = __builtin_amdgcn_mfma_f32_16x16x32_bf16(af[mi], bf[ni], acc[mi][ni], 0, 0, 0);
  }

#pragma unroll
  for (int ni = 0; ni < 2; ++ni) {
    const int lo = ohh + ni * 16 + l15;
    const float b = Bb[g * 1024 + ob + lo];
#pragma unroll
    for (int mi = 0; mi < 2; ++mi) {
      const int rloc = mi * 16 + oct * 4;
#pragma unroll
      for (int j = 0; j < 4; ++j)
        obuf[rloc + j][4 * lo + g] = acc[mi][ni][j] + b;
    }
  }
  __syncthreads();

#pragma unroll
  for (int i = 0; i < 4; ++i) {
    const int q = tid + i * 512;
    const int row = q >> 6, c4 = q & 63;
    const float4 v = *(const float4*)&obuf[row][c4 * 4];
    *(float4*)(Out + (size_t)(r0 + row) * OBS + 4 * ob + c4 * 4) = v;
  }
}

extern "C" void kernel_launch(void* const* d_in, const int* in_sizes, int n_in,
                              void* d_out, int out_size, void* d_ws, size_t ws_size,
                              hipStream_t stream) {
  const float* X          = (const float*)d_in[0];
  const float* eps        = (const float*)d_in[1];
  const int*   subset_idx = (const int*)  d_in[2];
  const float* enc_w1     = (const float*)d_in[3];
  const float* enc_b1     = (const float*)d_in[4];
  const float* enc_w2     = (const float*)d_in[5];
  const float* enc_b2     = (const float*)d_in[6];
  const float* dec_w1     = (const float*)d_in[7];
  const float* dec_b1     = (const float*)d_in[8];
  const float* dec_w2     = (const float*)d_in[9];
  const float* dec_b2     = (const float*)d_in[10];
  float* out = (float*)d_out;

  char* wsb = (char*)d_ws;
  unsigned short* Xt  = (unsigned short*)wsb;                              // 64 MB
  unsigned short* Hd  = (unsigned short*)(wsb + (64u << 20));              // 4 MB
  unsigned short* W1t = (unsigned short*)(wsb + (68u << 20));              // 1 MB
  unsigned short* W2t = (unsigned short*)(wsb + (69u << 20));              // 128 KB
  unsigned short* W3t = (unsigned short*)(wsb + (69u << 20) + (128u << 10)); // 32 KB
  unsigned short* W4t = (unsigned short*)(wsb + (69u << 20) + (160u << 10)); // 512 KB

  k_prep<<<3392, 256, 0, stream>>>(enc_w1, enc_w2, dec_w1, dec_w2,
                                   W1t, W2t, W3t, W4t);
  k_prepx<<<8192, 512, 0, stream>>>(X, Xt);
  k_enc<<<256, 512, 0, stream>>>(Xt, W1t, W2t, W3t, enc_b1, enc_b2, dec_b1,
                                 eps, subset_idx, Hd);
  k_dec2<<<dim3(256, 16), 512, 0, stream>>>(Hd, W4t, dec_b2, out);
}

// Round 6
// 121.449 us; speedup vs baseline: 1.2319x; 1.2319x over previous
//
#include <hip/hip_runtime.h>
#include <hip/hip_bf16.h>
#include <math.h>

#define B_TOT 8192
#define OBS   4096
#define NG    4
#define GSZ   1024
#define LATD  64
#define HDIM  128

typedef __attribute__((ext_vector_type(8))) short   short8_t;
typedef __attribute__((ext_vector_type(8))) unsigned short ushort8_t;
typedef __attribute__((ext_vector_type(4))) float   float4_t;

__constant__ int kMask[15] = {1,2,4,8, 3,5,9,6,10,12, 7,11,13,14, 15};

static __device__ __forceinline__ unsigned short f2b(float x) {
  __hip_bfloat16 b = __float2bfloat16(x);
  return *reinterpret_cast<unsigned short*>(&b);
}
static __device__ __forceinline__ unsigned int pack2(float lo, float hi) {
  return (unsigned int)f2b(lo) | ((unsigned int)f2b(hi) << 16);
}

// ---------------- weight prep: transpose + bf16 ----------------------------
#define N1 524288
#define N2 65536
#define N3 16384
#define N4 262144
__global__ __launch_bounds__(256) void k_prep(const float* __restrict__ w1,
                                              const float* __restrict__ w2,
                                              const float* __restrict__ w3,
                                              const float* __restrict__ w4,
                                              unsigned short* __restrict__ W1t,
                                              unsigned short* __restrict__ W2t,
                                              unsigned short* __restrict__ W3t,
                                              unsigned short* __restrict__ W4t) {
  const int i = blockIdx.x * 256 + threadIdx.x;
  if (i < N1) {
    const int g = i >> 17, rem = i & 131071;
    const int h = rem >> 10, k = rem & 1023;
    W1t[i] = f2b(w1[g * 131072 + k * 128 + h]);
  } else if (i < N1 + N2) {
    const int idx = i - N1;
    const int g = idx >> 14, rem = idx & 16383;
    const int o = rem >> 7, k = rem & 127;
    W2t[idx] = f2b(w2[g * 16384 + k * 128 + o]);
  } else if (i < N1 + N2 + N3) {
    const int idx = i - N1 - N2;
    const int g = idx >> 12, rem = idx & 4095;
    const int m = rem >> 6, k = rem & 63;
    W3t[idx] = f2b(w3[g * 4096 + k * 64 + m]);
  } else if (i < N1 + N2 + N3 + N4) {
    const int idx = i - N1 - N2 - N3;
    const int g = idx >> 16, rem = idx & 65535;
    const int o = rem >> 6, k = rem & 63;
    W4t[idx] = f2b(w4[g * 65536 + k * 1024 + o]);
  }
}

// ---------------- fused: enc1 -> enc2 -> PoE/sample -> dec1 ----------------
// 256 blocks x 512 thr. Block = 32 batch rows x all 512 h-cols.
// enc1: K in 8 chunks of 512 floats (128 k/group). Each row's HBM read per
// chunk is 2KB CONTIGUOUS (DRAM-friendly). De-interleave fp32->bf16 g-planes
// in LDS, double-buffered, ONE barrier per chunk, 32 MFMA/wave between
// barriers. B direct from L2-resident W1t.
struct EncLds {
  union {
    unsigned short lsA[2][4][32][136];   // dbuf: [g][row][128k + 8 pad]
    unsigned short hp[16][32][40];       // h planes: [ks*4+g][row][32 + pad]
    float mls[32][516];                  // means/logvars fp32
  } u;
  unsigned short zb[32][72];             // z bf16
};
__global__ __launch_bounds__(512) void k_enc(const float* __restrict__ X,
                                             const unsigned short* __restrict__ W1t,
                                             const unsigned short* __restrict__ W2t,
                                             const unsigned short* __restrict__ W3t,
                                             const float* __restrict__ B1,
                                             const float* __restrict__ B2,
                                             const float* __restrict__ DB1,
                                             const float* __restrict__ eps,
                                             const int*   __restrict__ subset_idx,
                                             unsigned short* __restrict__ Hd) {
  __shared__ EncLds s;
  const int tid = threadIdx.x;
  const int w   = tid >> 6;
  const int l   = tid & 63;
  const int g   = w >> 1;
  const int hh  = (w & 1) * 64;
  const int rb  = blockIdx.x * 32;
  const int l15 = l & 15;
  const int oct = l >> 4;

  // staging mapping: thread = (row, seg); reads 32 consecutive floats
  const int srow = tid >> 4;          // 0..31
  const int seg  = tid & 15;          // 0..15 (32-float segment)
  const float* xb = X + (size_t)(rb + srow) * OBS + seg * 32;

  float4_t q[8];
#pragma unroll
  for (int i = 0; i < 8; ++i) q[i] = *(const float4_t*)(xb + 4 * i);

  float4_t acc[2][4];
#pragma unroll
  for (int i = 0; i < 2; ++i)
#pragma unroll
    for (int j = 0; j < 4; ++j) acc[i][j] = (float4_t){0.f, 0.f, 0.f, 0.f};

  // write chunk 0 to buf 0: per g, shorts[j] = bf16(q[j][g]), k=seg*8..+8
#pragma unroll
  for (int gg = 0; gg < 4; ++gg) {
    uint4 val;
    val.x = pack2(q[0][gg], q[1][gg]);
    val.y = pack2(q[2][gg], q[3][gg]);
    val.z = pack2(q[4][gg], q[5][gg]);
    val.w = pack2(q[6][gg], q[7][gg]);
    *(uint4*)&s.u.lsA[0][gg][srow][seg * 8] = val;
  }
  __syncthreads();

  for (int c = 0; c < 8; ++c) {
    const int cur = c & 1;
    // issue next chunk's 2KB-contiguous row reads early
    if (c < 7) {
#pragma unroll
      for (int i = 0; i < 8; ++i)
        q[i] = *(const float4_t*)(xb + (c + 1) * 512 + 4 * i);
    }

    // 4 ksteps x 8 MFMA on buf[cur]
#pragma unroll
    for (int ks = 0; ks < 4; ++ks) {
      short8_t af[2], bf[4];
#pragma unroll
      for (int mi = 0; mi < 2; ++mi)
        af[mi] = *(const short8_t*)&s.u.lsA[cur][g][mi * 16 + l15][ks * 32 + oct * 8];
#pragma unroll
      for (int ni = 0; ni < 4; ++ni)
        bf[ni] = *(const short8_t*)(W1t +
                  (size_t)(g * 128 + hh + ni * 16 + l15) * GSZ +
                  c * 128 + ks * 32 + oct * 8);
#pragma unroll
      for (int mi = 0; mi < 2; ++mi)
#pragma unroll
        for (int ni = 0; ni < 4; ++ni)
          acc[mi][ni] = __builtin_amdgcn_mfma_f32_16x16x32_bf16(af[mi], bf[ni], acc[mi][ni], 0, 0, 0);
    }

    // write next chunk into the other buffer
    if (c < 7) {
#pragma unroll
      for (int gg = 0; gg < 4; ++gg) {
        uint4 val;
        val.x = pack2(q[0][gg], q[1][gg]);
        val.y = pack2(q[2][gg], q[3][gg]);
        val.z = pack2(q[4][gg], q[5][gg]);
        val.w = pack2(q[6][gg], q[7][gg]);
        *(uint4*)&s.u.lsA[cur ^ 1][gg][srow][seg * 8] = val;
      }
    }
    __syncthreads();
  }

  // h = relu(acc + b1) -> hp planes (aliases lsA; all reads done)
#pragma unroll
  for (int ni = 0; ni < 4; ++ni) {
    const int cg    = hh + ni * 16 + l15;     // 0..127 within group
    const int plane = (cg >> 5) * 4 + g;
    const int off   = cg & 31;
    const float b   = B1[g * 128 + cg];
#pragma unroll
    for (int mi = 0; mi < 2; ++mi) {
      const int row = mi * 16 + oct * 4;
#pragma unroll
      for (int j = 0; j < 4; ++j)
        s.u.hp[plane][row + j][off] = f2b(fmaxf(acc[mi][ni][j] + b, 0.0f));
    }
  }
  __syncthreads();

  // ---- enc2: K=128 (own group), 4 ksteps, B direct from L2-resident W2t ----
#pragma unroll
  for (int i = 0; i < 2; ++i)
#pragma unroll
    for (int j = 0; j < 4; ++j) acc[i][j] = (float4_t){0.f, 0.f, 0.f, 0.f};
  {
    const unsigned short* bbase = W2t + (size_t)(g * 128 + hh + l15) * HDIM + oct * 8;
#pragma unroll
    for (int ks = 0; ks < 4; ++ks) {
      short8_t af[2], bf[4];
#pragma unroll
      for (int mi = 0; mi < 2; ++mi)
        af[mi] = *(const short8_t*)(&s.u.hp[ks * 4 + g][mi * 16 + l15][oct * 8]);
#pragma unroll
      for (int ni = 0; ni < 4; ++ni)
        bf[ni] = *(const short8_t*)(bbase + (size_t)ni * 16 * HDIM + ks * 32);
#pragma unroll
      for (int mi = 0; mi < 2; ++mi)
#pragma unroll
        for (int ni = 0; ni < 4; ++ni)
          acc[mi][ni] = __builtin_amdgcn_mfma_f32_16x16x32_bf16(af[mi], bf[ni], acc[mi][ni], 0, 0, 0);
    }
  }
  __syncthreads();   // done reading hp; mls overlays it

#pragma unroll
  for (int ni = 0; ni < 4; ++ni) {
    const int col = g * 128 + hh + ni * 16 + l15;
    const float b = B2[col];
#pragma unroll
    for (int mi = 0; mi < 2; ++mi)
#pragma unroll
      for (int j = 0; j < 4; ++j)
        s.u.mls[mi * 16 + oct * 4 + j][col] = acc[mi][ni][j] + b;
  }
  __syncthreads();

  // ---- PoE + reparameterize -> zb (bf16) ----
#pragma unroll
  for (int qq = 0; qq < 4; ++qq) {
    const int idx = qq * 512 + tid;
    const int r   = idx >> 6;
    const int ll  = idx & 63;
    const int m   = kMask[subset_idx[rb + r]];
    float tau = 1.0f, num = 0.0f;
#pragma unroll
    for (int gg = 0; gg < 4; ++gg) {
      if (m & (1 << gg)) {
        const float lv = s.u.mls[r][gg * 128 + 64 + ll];
        const float mu = s.u.mls[r][gg * 128 + ll];
        const float t  = expf(-lv);
        tau += t;
        num = fmaf(t, mu, num);
      }
    }
    const float zv = num / tau + eps[(size_t)(rb + r) * LATD + ll] * rsqrtf(tau);
    s.zb[r][ll] = f2b(zv);
  }
  __syncthreads();

  // ---- dec1: K=64, 2 ksteps -> Hd bf16 ----
  const int mh = (w & 1) * 32;
  float4_t a3[2][2];
#pragma unroll
  for (int i = 0; i < 2; ++i)
#pragma unroll
    for (int j = 0; j < 2; ++j) a3[i][j] = (float4_t){0.f, 0.f, 0.f, 0.f};
  {
    const unsigned short* bbase = W3t + (size_t)(g * 64 + mh + l15) * LATD + oct * 8;
#pragma unroll
    for (int ks = 0; ks < 2; ++ks) {
      short8_t af[2], bf[2];
#pragma unroll
      for (int mi = 0; mi < 2; ++mi)
        af[mi] = *(const short8_t*)(&s.zb[mi * 16 + l15][ks * 32 + oct * 8]);
#pragma unroll
      for (int ni = 0; ni < 2; ++ni)
        bf[ni] = *(const short8_t*)(bbase + (size_t)ni * 16 * LATD + ks * 32);
#pragma unroll
      for (int mi = 0; mi < 2; ++mi)
#pragma unroll
        for (int ni = 0; ni < 2; ++ni)
          a3[mi][ni] = __builtin_amdgcn_mfma_f32_16x16x32_bf16(af[mi], bf[ni], a3[mi][ni], 0, 0, 0);
    }
  }
#pragma unroll
  for (int ni = 0; ni < 2; ++ni) {
    const int col = g * 64 + mh + ni * 16 + l15;   // 0..255
    const float b = DB1[col];
#pragma unroll
    for (int mi = 0; mi < 2; ++mi) {
      const int row = mi * 16 + oct * 4;
#pragma unroll
      for (int j = 0; j < 4; ++j)
        Hd[(size_t)(rb + row + j) * 256 + col] = f2b(fmaxf(a3[mi][ni][j] + b, 0.0f));
    }
  }
}

// ---------------- dec2: direct-global MFMA + coalesced epilogue ------------
__global__ __launch_bounds__(512) void k_dec2(const unsigned short* __restrict__ Hd,
                                              const unsigned short* __restrict__ W4t,
                                              const float* __restrict__ Bb,
                                              float* __restrict__ Out) {
  __shared__ float obuf[32][264];

  const int tid = threadIdx.x;
  const int w   = tid >> 6;
  const int l   = tid & 63;
  const int g   = w >> 1;
  const int ohh = (w & 1) * 32;
  const int r0  = blockIdx.x * 32;
  const int ob  = blockIdx.y * 64;
  const int l15 = l & 15;
  const int oct = l >> 4;

  float4_t acc[2][2];
#pragma unroll
  for (int i = 0; i < 2; ++i)
#pragma unroll
    for (int j = 0; j < 2; ++j) acc[i][j] = (float4_t){0.f, 0.f, 0.f, 0.f};

#pragma unroll
  for (int ks = 0; ks < 2; ++ks) {
    short8_t af[2], bf[2];
#pragma unroll
    for (int mi = 0; mi < 2; ++mi)
      af[mi] = *(const short8_t*)(Hd + (size_t)(r0 + mi * 16 + l15) * 256 +
                                  g * 64 + ks * 32 + oct * 8);
#pragma unroll
    for (int ni = 0; ni < 2; ++ni)
      bf[ni] = *(const short8_t*)(W4t + (size_t)(g * 1024 + ob + ohh + ni * 16 + l15) * 64 +
                                  ks * 32 + oct * 8);
#pragma unroll
    for (int mi = 0; mi < 2; ++mi)
#pragma unroll
      for (int ni = 0; ni < 2; ++ni)
        acc[mi][ni] = __builtin_amdgcn_mfma_f32_16x16x32_bf16(af[mi], bf[ni], acc[mi][ni], 0, 0, 0);
  }

#pragma unroll
  for (int ni = 0; ni < 2; ++ni) {
    const int lo = ohh + ni * 16 + l15;
    const float b = Bb[g * 1024 + ob + lo];
#pragma unroll
    for (int mi = 0; mi < 2; ++mi) {
      const int rloc = mi * 16 + oct * 4;
#pragma unroll
      for (int j = 0; j < 4; ++j)
        obuf[rloc + j][4 * lo + g] = acc[mi][ni][j] + b;
    }
  }
  __syncthreads();

#pragma unroll
  for (int i = 0; i < 4; ++i) {
    const int q = tid + i * 512;
    const int row = q >> 6, c4 = q & 63;
    const float4 v = *(const float4*)&obuf[row][c4 * 4];
    *(float4*)(Out + (size_t)(r0 + row) * OBS + 4 * ob + c4 * 4) = v;
  }
}

extern "C" void kernel_launch(void* const* d_in, const int* in_sizes, int n_in,
                              void* d_out, int out_size, void* d_ws, size_t ws_size,
                              hipStream_t stream) {
  const float* X          = (const float*)d_in[0];
  const float* eps        = (const float*)d_in[1];
  const int*   subset_idx = (const int*)  d_in[2];
  const float* enc_w1     = (const float*)d_in[3];
  const float* enc_b1     = (const float*)d_in[4];
  const float* enc_w2     = (const float*)d_in[5];
  const float* enc_b2     = (const float*)d_in[6];
  const float* dec_w1     = (const float*)d_in[7];
  const float* dec_b1     = (const float*)d_in[8];
  const float* dec_w2     = (const float*)d_in[9];
  const float* dec_b2     = (const float*)d_in[10];
  float* out = (float*)d_out;

  char* wsb = (char*)d_ws;
  unsigned short* Hd  = (unsigned short*)wsb;                                // 4 MB
  unsigned short* W1t = (unsigned short*)(wsb + (4u << 20));                 // 1 MB
  unsigned short* W2t = (unsigned short*)(wsb + (5u << 20));                 // 128 KB
  unsigned short* W3t = (unsigned short*)(wsb + (5u << 20) + (128u << 10));  // 32 KB
  unsigned short* W4t = (unsigned short*)(wsb + (5u << 20) + (160u << 10));  // 512 KB

  k_prep<<<3392, 256, 0, stream>>>(enc_w1, enc_w2, dec_w1, dec_w2,
                                   W1t, W2t, W3t, W4t);
  k_enc<<<256, 512, 0, stream>>>(X, W1t, W2t, W3t, enc_b1, enc_b2, dec_b1,
                                 eps, subset_idx, Hd);
  k_dec2<<<dim3(256, 16), 512, 0, stream>>>(Hd, W4t, dec_b2, out);
}

// Round 7
// 103.513 us; speedup vs baseline: 1.4453x; 1.1733x over previous
//
#include <hip/hip_runtime.h>
#include <hip/hip_bf16.h>
#include <math.h>

#define B_TOT 8192
#define OBS   4096
#define NG    4
#define GSZ   1024
#define LATD  64
#define HDIM  128

#define RS   136    // lA row stride (shorts), 272B = 16B-aligned
#define PLA  2184   // lA plane stride (16*136+8): word%32==4 stagger
#define PSH  648    // hp plane stride (16*40+8): 1296B, 16B-aligned

typedef __attribute__((ext_vector_type(8))) short   short8_t;
typedef __attribute__((ext_vector_type(8))) unsigned short ushort8_t;
typedef __attribute__((ext_vector_type(4))) float   float4_t;

__constant__ int kMask[15] = {1,2,4,8, 3,5,9,6,10,12, 7,11,13,14, 15};

static __device__ __forceinline__ unsigned short f2b(float x) {
  __hip_bfloat16 b = __float2bfloat16(x);
  return *reinterpret_cast<unsigned short*>(&b);
}
static __device__ __forceinline__ unsigned int pack2(float lo, float hi) {
  return (unsigned int)f2b(lo) | ((unsigned int)f2b(hi) << 16);
}

// ------------- weight prep: transpose + bf16 + fragment-panel layout -------
// Panels: 1KB per (ks,ni) fragment-slot group = [l15 16][oct 4][j 8] shorts,
// so each wave B-load is 64 lanes x 16B CONTIGUOUS.
// W1p additionally applies the k-permutation logical_k = (j&3)*32+ks*8+oct*2+(j>>2)
// (matches A staging phys order p=seg*4+t <-> k=t*32+seg).
#define N1 524288
#define N2 65536
#define N3 16384
#define N4 262144
__global__ __launch_bounds__(256) void k_prep(const float* __restrict__ w1,
                                              const float* __restrict__ w2,
                                              const float* __restrict__ w3,
                                              const float* __restrict__ w4,
                                              unsigned short* __restrict__ W1p,
                                              unsigned short* __restrict__ W2p,
                                              unsigned short* __restrict__ W3p,
                                              unsigned short* __restrict__ W4p) {
  const int i = blockIdx.x * 256 + threadIdx.x;
  if (i < N1) {
    const int j = i & 7, oct = (i >> 3) & 3, l15 = (i >> 5) & 15;
    const int ni = (i >> 9) & 3, ks = (i >> 11) & 3, c = (i >> 13) & 7;
    const int h2 = (i >> 16) & 1, g = (i >> 17) & 3;
    const int k = c * 128 + (j & 3) * 32 + ks * 8 + oct * 2 + (j >> 2);  // perm
    const int h = h2 * 64 + ni * 16 + l15;
    W1p[i] = f2b(w1[g * 131072 + k * 128 + h]);
  } else if (i < N1 + N2) {
    const int idx = i - N1;
    const int j = idx & 7, oct = (idx >> 3) & 3, l15 = (idx >> 5) & 15;
    const int ni = (idx >> 9) & 3, ks = (idx >> 11) & 3;
    const int h2 = (idx >> 13) & 1, g = (idx >> 14) & 3;
    const int k = ks * 32 + oct * 8 + j;                                 // identity
    const int h = h2 * 64 + ni * 16 + l15;
    W2p[idx] = f2b(w2[g * 16384 + k * 128 + h]);
  } else if (i < N1 + N2 + N3) {
    const int idx = i - N1 - N2;
    const int j = idx & 7, oct = (idx >> 3) & 3, l15 = (idx >> 5) & 15;
    const int ni = (idx >> 9) & 1, ks = (idx >> 10) & 1;
    const int h2 = (idx >> 11) & 1, g = (idx >> 12) & 3;
    const int k = ks * 32 + oct * 8 + j;
    const int m = h2 * 32 + ni * 16 + l15;
    W3p[idx] = f2b(w3[g * 4096 + k * 64 + m]);
  } else if (i < N1 + N2 + N3 + N4) {
    const int idx = i - N1 - N2 - N3;
    const int j = idx & 7, oct = (idx >> 3) & 3, l15 = (idx >> 5) & 15;
    const int ni = (idx >> 9) & 1, ks = (idx >> 10) & 1;
    const int oh = (idx >> 11) & 1, ob = (idx >> 12) & 15, g = (idx >> 16) & 3;
    const int k = ks * 32 + oct * 8 + j;
    const int o = ob * 64 + oh * 32 + ni * 16 + l15;
    W4p[idx] = f2b(w4[g * 65536 + k * 1024 + o]);
  }
}

// ---------------- fused: enc1 -> enc2 -> PoE/sample -> dec1 ----------------
// 512 blocks (2/CU) x 512 thr. Block = 16 batch rows. Wave: g=w>>1, h2=w&1.
struct EncLds {
  union {
    unsigned short lA[2][4 * PLA];   // enc1 A dbuf (phys-k order)
    unsigned short hp[16 * PSH];     // h planes [ks*4+g][row][32+pad]
    float mls[16][516];
  } u;
  unsigned short zb[16][72];
};
__global__ __launch_bounds__(512, 4) void k_enc(const float* __restrict__ X,
                                                const unsigned short* __restrict__ W1p,
                                                const unsigned short* __restrict__ W2p,
                                                const unsigned short* __restrict__ W3p,
                                                const float* __restrict__ B1,
                                                const float* __restrict__ B2,
                                                const float* __restrict__ DB1,
                                                const float* __restrict__ eps,
                                                const int*   __restrict__ subset_idx,
                                                unsigned short* __restrict__ Hd) {
  __shared__ EncLds s;
  const int tid = threadIdx.x;
  const int w   = tid >> 6;
  const int l   = tid & 63;
  const int g   = w >> 1;
  const int h2  = w & 1;
  const int rb  = blockIdx.x * 16;
  const int l15 = l & 15;
  const int oct = l >> 4;
  const int lofs = (l15 * 4 + oct) * 8;     // panel lane offset (shorts)

  // staging map: thread = (row, seg); instr t reads 512B-contiguous runs
  const int srow = tid >> 5;          // 0..15
  const int seg  = tid & 31;          // 0..31
  const float* xb = X + (size_t)(rb + srow) * OBS + seg * 4;

  float4_t q0, q1, q2, q3;
  q0 = *(const float4_t*)(xb + 0);
  q1 = *(const float4_t*)(xb + 128);
  q2 = *(const float4_t*)(xb + 256);
  q3 = *(const float4_t*)(xb + 384);
  {
#pragma unroll
    for (int gg = 0; gg < 4; ++gg) {
      uint2 v;
      v.x = pack2(q0[gg], q1[gg]);
      v.y = pack2(q2[gg], q3[gg]);
      *(uint2*)&s.u.lA[0][gg * PLA + srow * RS + seg * 4] = v;
    }
  }

  float4_t acc[4];
#pragma unroll
  for (int j = 0; j < 4; ++j) acc[j] = (float4_t){0.f, 0.f, 0.f, 0.f};

  const unsigned short* bb1 = W1p + (g * 2 + h2) * 65536 + lofs;

  for (int c = 0; c < 8; ++c) {
    __syncthreads();
    const int cur = c & 1;
    if (c < 7) {   // issue next chunk's loads (2x512B contiguous per instr)
      const float* xn = xb + (c + 1) * 512;
      q0 = *(const float4_t*)(xn + 0);
      q1 = *(const float4_t*)(xn + 128);
      q2 = *(const float4_t*)(xn + 256);
      q3 = *(const float4_t*)(xn + 384);
    }
#pragma unroll
    for (int ks = 0; ks < 4; ++ks) {
      const short8_t af = *(const short8_t*)&s.u.lA[cur][g * PLA + l15 * RS + ks * 32 + oct * 8];
      short8_t bf[4];
#pragma unroll
      for (int ni = 0; ni < 4; ++ni)
        bf[ni] = *(const short8_t*)(bb1 + c * 8192 + ks * 2048 + ni * 512);
#pragma unroll
      for (int ni = 0; ni < 4; ++ni)
        acc[ni] = __builtin_amdgcn_mfma_f32_16x16x32_bf16(af, bf[ni], acc[ni], 0, 0, 0);
    }
    if (c < 7) {
#pragma unroll
      for (int gg = 0; gg < 4; ++gg) {
        uint2 v;
        v.x = pack2(q0[gg], q1[gg]);
        v.y = pack2(q2[gg], q3[gg]);
        *(uint2*)&s.u.lA[cur ^ 1][gg * PLA + srow * RS + seg * 4] = v;
      }
    }
  }
  __syncthreads();

  // h = relu(acc+b1) -> hp planes (overlay lA)
#pragma unroll
  for (int ni = 0; ni < 4; ++ni) {
    const int hcol = h2 * 64 + ni * 16 + l15;       // 0..127
    const float b  = B1[g * 128 + hcol];
    const int plane = (hcol >> 5) * 4 + g;
    const int off   = hcol & 31;
#pragma unroll
    for (int j = 0; j < 4; ++j)
      s.u.hp[plane * PSH + (oct * 4 + j) * 40 + off] = f2b(fmaxf(acc[ni][j] + b, 0.0f));
  }
  __syncthreads();

  // ---- enc2: K=128, 4 ksteps; B panel loads (contiguous 1KB) ----
#pragma unroll
  for (int j = 0; j < 4; ++j) acc[j] = (float4_t){0.f, 0.f, 0.f, 0.f};
  {
    const unsigned short* bb2 = W2p + (g * 2 + h2) * 8192 + lofs;
#pragma unroll
    for (int ks = 0; ks < 4; ++ks) {
      const short8_t af = *(const short8_t*)&s.u.hp[(ks * 4 + g) * PSH + l15 * 40 + oct * 8];
#pragma unroll
      for (int ni = 0; ni < 4; ++ni) {
        const short8_t bf = *(const short8_t*)(bb2 + ks * 2048 + ni * 512);
        acc[ni] = __builtin_amdgcn_mfma_f32_16x16x32_bf16(af, bf, acc[ni], 0, 0, 0);
      }
    }
  }
  __syncthreads();   // done reading hp; mls overlays

#pragma unroll
  for (int ni = 0; ni < 4; ++ni) {
    const int col = g * 128 + h2 * 64 + ni * 16 + l15;
    const float b = B2[col];
#pragma unroll
    for (int j = 0; j < 4; ++j)
      s.u.mls[oct * 4 + j][col] = acc[ni][j] + b;
  }
  __syncthreads();

  // ---- PoE + reparameterize -> zb ----
#pragma unroll
  for (int qq = 0; qq < 2; ++qq) {
    const int idx = qq * 512 + tid;
    const int r   = idx >> 6;
    const int ll  = idx & 63;
    const int m   = kMask[subset_idx[rb + r]];
    float tau = 1.0f, num = 0.0f;
#pragma unroll
    for (int gg = 0; gg < 4; ++gg) {
      if (m & (1 << gg)) {
        const float lv = s.u.mls[r][gg * 128 + 64 + ll];
        const float mu = s.u.mls[r][gg * 128 + ll];
        const float t  = expf(-lv);
        tau += t;
        num = fmaf(t, mu, num);
      }
    }
    const float zv = num / tau + eps[(size_t)(rb + r) * LATD + ll] * rsqrtf(tau);
    s.zb[r][ll] = f2b(zv);
  }
  __syncthreads();

  // ---- dec1: K=64, 2 ksteps -> Hd ----
  float4_t a3[2];
  a3[0] = (float4_t){0.f, 0.f, 0.f, 0.f};
  a3[1] = (float4_t){0.f, 0.f, 0.f, 0.f};
  {
    const unsigned short* bb3 = W3p + (g * 2 + h2) * 2048 + lofs;
#pragma unroll
    for (int ks = 0; ks < 2; ++ks) {
      const short8_t af = *(const short8_t*)&s.zb[l15][ks * 32 + oct * 8];
#pragma unroll
      for (int ni = 0; ni < 2; ++ni) {
        const short8_t bf = *(const short8_t*)(bb3 + ks * 1024 + ni * 512);
        a3[ni] = __builtin_amdgcn_mfma_f32_16x16x32_bf16(af, bf, a3[ni], 0, 0, 0);
      }
    }
  }
#pragma unroll
  for (int ni = 0; ni < 2; ++ni) {
    const int col = g * 64 + h2 * 32 + ni * 16 + l15;   // 0..255
    const float b = DB1[col];
#pragma unroll
    for (int j = 0; j < 4; ++j)
      Hd[(size_t)(rb + oct * 4 + j) * 256 + col] = f2b(fmaxf(a3[ni][j] + b, 0.0f));
  }
}

// ---------------- dec2: panel-B MFMA + coalesced epilogue ------------------
__global__ __launch_bounds__(512) void k_dec2(const unsigned short* __restrict__ Hd,
                                              const unsigned short* __restrict__ W4p,
                                              const float* __restrict__ Bb,
                                              float* __restrict__ Out) {
  __shared__ float obuf[32][264];

  const int tid = threadIdx.x;
  const int w   = tid >> 6;
  const int l   = tid & 63;
  const int g   = w >> 1;
  const int oh  = w & 1;
  const int r0  = blockIdx.x * 32;
  const int ob  = blockIdx.y * 64;
  const int l15 = l & 15;
  const int oct = l >> 4;
  const int lofs = (l15 * 4 + oct) * 8;

  float4_t acc[2][2];
#pragma unroll
  for (int i = 0; i < 2; ++i)
#pragma unroll
    for (int j = 0; j < 2; ++j) acc[i][j] = (float4_t){0.f, 0.f, 0.f, 0.f};

  const unsigned short* bb4 = W4p + ((g * 16 + blockIdx.y) * 2 + oh) * 2048 + lofs;

#pragma unroll
  for (int ks = 0; ks < 2; ++ks) {
    short8_t af[2], bf[2];
#pragma unroll
    for (int mi = 0; mi < 2; ++mi)
      af[mi] = *(const short8_t*)(Hd + (size_t)(r0 + mi * 16 + l15) * 256 +
                                  g * 64 + ks * 32 + oct * 8);
#pragma unroll
    for (int ni = 0; ni < 2; ++ni)
      bf[ni] = *(const short8_t*)(bb4 + ks * 1024 + ni * 512);
#pragma unroll
    for (int mi = 0; mi < 2; ++mi)
#pragma unroll
      for (int ni = 0; ni < 2; ++ni)
        acc[mi][ni] = __builtin_amdgcn_mfma_f32_16x16x32_bf16(af[mi], bf[ni], acc[mi][ni], 0, 0, 0);
  }

#pragma unroll
  for (int ni = 0; ni < 2; ++ni) {
    const int lo = oh * 32 + ni * 16 + l15;
    const float b = Bb[g * 1024 + ob + lo];
#pragma unroll
    for (int mi = 0; mi < 2; ++mi) {
      const int rloc = mi * 16 + oct * 4;
#pragma unroll
      for (int j = 0; j < 4; ++j)
        obuf[rloc + j][4 * lo + g] = acc[mi][ni][j] + b;
    }
  }
  __syncthreads();

#pragma unroll
  for (int i = 0; i < 4; ++i) {
    const int q = tid + i * 512;
    const int row = q >> 6, c4 = q & 63;
    const float4 v = *(const float4*)&obuf[row][c4 * 4];
    *(float4*)(Out + (size_t)(r0 + row) * OBS + 4 * ob + c4 * 4) = v;
  }
}

extern "C" void kernel_launch(void* const* d_in, const int* in_sizes, int n_in,
                              void* d_out, int out_size, void* d_ws, size_t ws_size,
                              hipStream_t stream) {
  const float* X          = (const float*)d_in[0];
  const float* eps        = (const float*)d_in[1];
  const int*   subset_idx = (const int*)  d_in[2];
  const float* enc_w1     = (const float*)d_in[3];
  const float* enc_b1     = (const float*)d_in[4];
  const float* enc_w2     = (const float*)d_in[5];
  const float* enc_b2     = (const float*)d_in[6];
  const float* dec_w1     = (const float*)d_in[7];
  const float* dec_b1     = (const float*)d_in[8];
  const float* dec_w2     = (const float*)d_in[9];
  const float* dec_b2     = (const float*)d_in[10];
  float* out = (float*)d_out;

  char* wsb = (char*)d_ws;
  unsigned short* Hd  = (unsigned short*)wsb;                                // 4 MB
  unsigned short* W1p = (unsigned short*)(wsb + (4u << 20));                 // 1 MB
  unsigned short* W2p = (unsigned short*)(wsb + (5u << 20));                 // 128 KB
  unsigned short* W3p = (unsigned short*)(wsb + (5u << 20) + (128u << 10));  // 32 KB
  unsigned short* W4p = (unsigned short*)(wsb + (5u << 20) + (160u << 10));  // 512 KB

  k_prep<<<3392, 256, 0, stream>>>(enc_w1, enc_w2, dec_w1, dec_w2,
                                   W1p, W2p, W3p, W4p);
  k_enc<<<512, 512, 0, stream>>>(X, W1p, W2p, W3p, enc_b1, enc_b2, dec_b1,
                                 eps, subset_idx, Hd);
  k_dec2<<<dim3(256, 16), 512, 0, stream>>>(Hd, W4p, dec_b2, out);
}